// Round 1
// baseline (249.327 us; speedup 1.0000x reference)
//
#include <hip/hip_runtime.h>

typedef unsigned short u16;
typedef __attribute__((ext_vector_type(8))) short bf16x8;
typedef __attribute__((ext_vector_type(4))) float f32x4;
typedef __attribute__((ext_vector_type(8))) unsigned short u16x8;
typedef __attribute__((ext_vector_type(4))) unsigned short u16x4;
typedef __attribute__((ext_vector_type(2))) unsigned short u16x2;

// ---- bf16 helpers (RNE) ----
__device__ __forceinline__ u16 f2b(float f) {
  unsigned u = __builtin_bit_cast(unsigned, f);
  unsigned r = (u + 0x7fffu + ((u >> 16) & 1u)) >> 16;
  return (u16)r;
}
__device__ __forceinline__ float b2f(u16 u) {
  return __builtin_bit_cast(float, ((unsigned)u) << 16);
}
__device__ __forceinline__ void gload16(const void* g, void* l) {
  __builtin_amdgcn_global_load_lds(
      (const __attribute__((address_space(1))) unsigned int*)g,
      (__attribute__((address_space(3))) unsigned int*)l, 16, 0, 0);
}

// ---- cast f32 -> bf16, 4 elems/thread ----
__global__ __launch_bounds__(256) void k_cast(const float* __restrict__ in,
                                              u16* __restrict__ out, int n4) {
  int i = blockIdx.x * 256 + threadIdx.x;
  if (i >= n4) return;
  float4 v = ((const float4*)in)[i];
  u16x4 o;
  o.x = f2b(v.x); o.y = f2b(v.y); o.z = f2b(v.z); o.w = f2b(v.w);
  ((u16x4*)out)[i] = o;
}

// ---- transpose + cast: in (M x N) f32 -> out (N x M) bf16 ----
__global__ __launch_bounds__(256) void k_transpose_cast(const float* __restrict__ in,
                                                        u16* __restrict__ out, int M, int N) {
  __shared__ float t[32][33];
  int c0 = blockIdx.x * 32, r0 = blockIdx.y * 32;
  int tx = threadIdx.x, ty = threadIdx.y;  // block (32,8)
  for (int ii = 0; ii < 4; ++ii) {
    int i = ty + ii * 8;
    t[i][tx] = in[(size_t)(r0 + i) * N + c0 + tx];
  }
  __syncthreads();
  for (int ii = 0; ii < 4; ++ii) {
    int i = ty + ii * 8;
    out[(size_t)(c0 + i) * M + r0 + tx] = f2b(t[tx][i]);
  }
}

// ---- GEMM: C[M,N] = A[M,K](bf16,row) * Bt[N,K](bf16,row, i.e. B transposed) ----
// m97 structure: 128x128 tile, BK=32, 4 waves 2x2, 16x16x32 bf16 MFMA.
template<int OUT_BF16>
__global__ __launch_bounds__(256) void k_gemm_bt(const u16* __restrict__ A,
                                                 const u16* __restrict__ Bt,
                                                 void* __restrict__ Cv,
                                                 int M, int N, int K) {
  __shared__ u16 lA[128 * 32];
  __shared__ u16 lB[128 * 32];
  const int tid = threadIdx.x;
  const int lane = tid & 63, w = tid >> 6;
  const int wr = w >> 1, wc = w & 1;
  const int la = lane & 15, hi = lane >> 4;
  const int bm0 = blockIdx.y * 128, bn0 = blockIdx.x * 128;
  const f32x4 zero = {0.f, 0.f, 0.f, 0.f};
  f32x4 acc[4][4];
#pragma unroll
  for (int m = 0; m < 4; ++m)
#pragma unroll
    for (int n = 0; n < 4; ++n) acc[m][n] = zero;

  const int r0 = tid >> 2;          // staging row (0..63), +64 on iter 1
  const int c8 = (tid & 3) * 8;     // staging col chunk
  for (int k0 = 0; k0 < K; k0 += 32) {
    gload16(A  + (size_t)(bm0 + r0)      * K + k0 + c8, &lA[tid * 8]);
    gload16(A  + (size_t)(bm0 + r0 + 64) * K + k0 + c8, &lA[(tid + 256) * 8]);
    gload16(Bt + (size_t)(bn0 + r0)      * K + k0 + c8, &lB[tid * 8]);
    gload16(Bt + (size_t)(bn0 + r0 + 64) * K + k0 + c8, &lB[(tid + 256) * 8]);
    __syncthreads();
    bf16x8 af[4], bfr[4];
#pragma unroll
    for (int m = 0; m < 4; ++m)
      af[m] = *(const bf16x8*)&lA[(wr * 64 + m * 16 + la) * 32 + hi * 8];
#pragma unroll
    for (int n = 0; n < 4; ++n)
      bfr[n] = *(const bf16x8*)&lB[(wc * 64 + n * 16 + la) * 32 + hi * 8];
#pragma unroll
    for (int m = 0; m < 4; ++m)
#pragma unroll
      for (int n = 0; n < 4; ++n)
        acc[m][n] = __builtin_amdgcn_mfma_f32_16x16x32_bf16(af[m], bfr[n], acc[m][n], 0, 0, 0);
    __syncthreads();
  }
  float* Cf = (float*)Cv;
  u16*   Cb = (u16*)Cv;
#pragma unroll
  for (int m = 0; m < 4; ++m)
#pragma unroll
    for (int n = 0; n < 4; ++n)
#pragma unroll
      for (int j = 0; j < 4; ++j) {
        int row = bm0 + wr * 64 + m * 16 + hi * 4 + j;
        int col = bn0 + wc * 64 + n * 16 + la;
        float v = acc[m][n][j];
        if (OUT_BF16) Cb[(size_t)row * N + col] = f2b(v);
        else          Cf[(size_t)row * N + col] = v;
      }
}

// ---- RoPE (interleaved pairs) + RMS-norm, qkv bf16 -> Q/K/V bf16 head-major ----
// grid (B*T, 6), block 128: 4 heads/block, 32 lanes/head (1 pair/lane).
__global__ __launch_bounds__(128) void k_rope_rms(const u16* __restrict__ qkv,
                                                  u16* __restrict__ Qb,
                                                  u16* __restrict__ Kb,
                                                  u16* __restrict__ Vb) {
  const int row = blockIdx.x;        // b*T + t
  const int grp = blockIdx.y;        // 0..3: q heads, 4: k, 5: v
  const int tid = threadIdx.x;
  const int sub = tid >> 5, i = tid & 31;
  const int b = row >> 11, t = row & 2047;
  int col, kind, head;
  if (grp < 4)       { head = grp * 4 + sub; col = head * 64;       kind = 0; }
  else if (grp == 4) { head = sub;           col = 1024 + sub * 64; kind = 1; }
  else               { head = sub;           col = 1280 + sub * 64; kind = 2; }
  u16x2 xv = *(const u16x2*)(qkv + (size_t)row * 1536 + col + 2 * i);
  float x0 = b2f(xv.x), x1 = b2f(xv.y);
  if (kind != 2) {
    // inv_freq = 10000^(-2i/64); ln(10000)/64 = 0.14391156831...
    float inv = expf((float)(2 * i) * -0.14391156831f);
    float fr = (float)t * inv;
    float s, c;
    sincosf(fr, &s, &c);
    float r0 = x0 * c - x1 * s;
    float r1 = x1 * c + x0 * s;
    x0 = r0; x1 = r1;
  }
  float ss = x0 * x0 + x1 * x1;
#pragma unroll
  for (int off = 16; off >= 1; off >>= 1) ss += __shfl_xor(ss, off, 32);
  float sc = (kind == 2) ? 1.0f : rsqrtf(ss * (1.0f / 64.0f) + 1e-6f);
  u16x2 o;
  o.x = f2b(x0 * sc); o.y = f2b(x1 * sc);
  size_t ob;
  if (kind == 0) ob = ((size_t)((b * 16 + head) * 2048 + t)) * 64 + 2 * i;
  else           ob = ((size_t)((b * 4  + head) * 2048 + t)) * 64 + 2 * i;
  u16* outp = (kind == 0) ? Qb : (kind == 1 ? Kb : Vb);
  *(u16x2*)(outp + ob) = o;
}

// ---- causal GQA flash attention ----
// grid (32 qtiles, B*NH=32), block 256 (4 waves x 16 q-rows). KV tiles of 64.
__global__ __launch_bounds__(256) void k_attn(const u16* __restrict__ Qb,
                                              const u16* __restrict__ Kb,
                                              const u16* __restrict__ Vb,
                                              u16* __restrict__ Ob) {
  __shared__ u16 lK[64][72];        // K tile, row-major, +8 pad
  __shared__ u16 lVt[64][72];       // V tile transposed: [hd][kv]
  __shared__ u16 lP[4][16][72];     // per-wave P (16 q-rows x 64 kv)
  const int bh = blockIdx.y;
  const int b = bh >> 4, h = bh & 15, g = h >> 2;
  const int qt0 = (int)(gridDim.x - 1 - blockIdx.x) * 64;  // heavy tiles first
  const int tid = threadIdx.x;
  const int lane = tid & 63, w = tid >> 6;
  const int la = lane & 15, hi = lane >> 4;

  const u16* Qg = Qb + ((size_t)(b * 16 + h) * 2048) * 64;
  const u16* Kg = Kb + ((size_t)(b * 4 + g) * 2048) * 64;
  const u16* Vg = Vb + ((size_t)(b * 4 + g) * 2048) * 64;

  bf16x8 qf0, qf1;
  {
    const u16* p = Qg + (size_t)(qt0 + w * 16 + la) * 64 + hi * 8;
    qf0 = *(const bf16x8*)p;
    qf1 = *(const bf16x8*)(p + 32);
  }
  float m_[4] = {-1e30f, -1e30f, -1e30f, -1e30f};
  float l_[4] = {0.f, 0.f, 0.f, 0.f};
  const f32x4 zero = {0.f, 0.f, 0.f, 0.f};
  f32x4 ao[4];
#pragma unroll
  for (int f = 0; f < 4; ++f) ao[f] = zero;

  const int sr  = tid >> 3;          // staging row 0..31 (+32 on iter 1)
  const int sc8 = (tid & 7) * 8;
  const int ntile = qt0 / 64 + 1;
  for (int kt = 0; kt < ntile; ++kt) {
    const int kv0 = kt * 64;
#pragma unroll
    for (int it = 0; it < 2; ++it) {
      int r = sr + it * 32;
      u16x8 kv = *(const u16x8*)(Kg + (size_t)(kv0 + r) * 64 + sc8);
      *(u16x8*)(&lK[r][sc8]) = kv;
      u16x8 vv = *(const u16x8*)(Vg + (size_t)(kv0 + r) * 64 + sc8);
#pragma unroll
      for (int e = 0; e < 8; ++e) lVt[sc8 + e][r] = vv[e];
    }
    __syncthreads();
    // S = Q K^T for this wave's 16 rows x 64 cols
    float p_[4][4];  // [n][j]
#pragma unroll
    for (int n = 0; n < 4; ++n) {
      bf16x8 kb0 = *(const bf16x8*)(&lK[n * 16 + la][hi * 8]);
      bf16x8 kb1 = *(const bf16x8*)(&lK[n * 16 + la][hi * 8 + 32]);
      f32x4 z = zero;
      z = __builtin_amdgcn_mfma_f32_16x16x32_bf16(qf0, kb0, z, 0, 0, 0);
      z = __builtin_amdgcn_mfma_f32_16x16x32_bf16(qf1, kb1, z, 0, 0, 0);
#pragma unroll
      for (int j = 0; j < 4; ++j) p_[n][j] = z[j] * 0.125f;
    }
    if (kt == ntile - 1) {  // diagonal tile: causal mask
#pragma unroll
      for (int n = 0; n < 4; ++n) {
        int colv = kv0 + n * 16 + la;
#pragma unroll
        for (int j = 0; j < 4; ++j) {
          int qrow = qt0 + w * 16 + hi * 4 + j;
          if (colv > qrow) p_[n][j] = -1e30f;
        }
      }
    }
    // online softmax per q-row (rows owned by 16-lane groups)
#pragma unroll
    for (int j = 0; j < 4; ++j) {
      float rm = fmaxf(fmaxf(p_[0][j], p_[1][j]), fmaxf(p_[2][j], p_[3][j]));
#pragma unroll
      for (int off = 1; off < 16; off <<= 1) rm = fmaxf(rm, __shfl_xor(rm, off, 16));
      float mn = fmaxf(m_[j], rm);
      float al = __expf(m_[j] - mn);
      float rs = 0.f;
#pragma unroll
      for (int n = 0; n < 4; ++n) {
        float p = __expf(p_[n][j] - mn);
        p_[n][j] = p;
        rs += p;
      }
#pragma unroll
      for (int off = 1; off < 16; off <<= 1) rs += __shfl_xor(rs, off, 16);
      l_[j] = l_[j] * al + rs;
      m_[j] = mn;
#pragma unroll
      for (int f = 0; f < 4; ++f) ao[f][j] *= al;
    }
    // P -> LDS (per-wave slice, in-wave RAW is ordered)
#pragma unroll
    for (int n = 0; n < 4; ++n)
#pragma unroll
      for (int j = 0; j < 4; ++j)
        lP[w][hi * 4 + j][n * 16 + la] = f2b(p_[n][j]);
    // PV: O += P * V
    bf16x8 pa0 = *(const bf16x8*)(&lP[w][la][hi * 8]);
    bf16x8 pa1 = *(const bf16x8*)(&lP[w][la][hi * 8 + 32]);
#pragma unroll
    for (int f = 0; f < 4; ++f) {
      bf16x8 v0 = *(const bf16x8*)(&lVt[f * 16 + la][hi * 8]);
      bf16x8 v1 = *(const bf16x8*)(&lVt[f * 16 + la][hi * 8 + 32]);
      ao[f] = __builtin_amdgcn_mfma_f32_16x16x32_bf16(pa0, v0, ao[f], 0, 0, 0);
      ao[f] = __builtin_amdgcn_mfma_f32_16x16x32_bf16(pa1, v1, ao[f], 0, 0, 0);
    }
    __syncthreads();
  }
  // epilogue: O row-major (b*T+t, h*64+hd) bf16 = GEMM2 A matrix
#pragma unroll
  for (int j = 0; j < 4; ++j) l_[j] = 1.0f / l_[j];
#pragma unroll
  for (int f = 0; f < 4; ++f)
#pragma unroll
    for (int j = 0; j < 4; ++j) {
      int row = qt0 + w * 16 + hi * 4 + j;
      Ob[((size_t)(b * 2048 + row)) * 1024 + h * 64 + f * 16 + la] = f2b(ao[f][j] * l_[j]);
    }
}

extern "C" void kernel_launch(void* const* d_in, const int* in_sizes, int n_in,
                              void* d_out, int out_size, void* d_ws, size_t ws_size,
                              hipStream_t stream) {
  const float* x  = (const float*)d_in[0];   // (2,2048,1024) f32
  const float* wa = (const float*)d_in[1];   // (1024,1536)  f32
  const float* wp = (const float*)d_in[2];   // (1024,1024)  f32
  float* out = (float*)d_out;                // (2,2048,1024) f32
  char* ws = (char*)d_ws;
  u16* xb   = (u16*)(ws + 0);          // 4096x1024 bf16   (8,388,608 B)
  u16* waT  = (u16*)(ws + 8388608);    // 1536x1024 bf16   (3,145,728 B)
  u16* wpT  = (u16*)(ws + 11534336);   // 1024x1024 bf16   (2,097,152 B)
  u16* qkvb = (u16*)(ws + 13631488);   // 4096x1536 bf16   (12,582,912 B)
  u16* Qb   = (u16*)(ws + 26214400);   // 2*16*2048*64 bf16 (8,388,608 B)
  u16* Kb   = (u16*)(ws + 34603008);   // 2*4*2048*64 bf16  (2,097,152 B)
  u16* Vb   = (u16*)(ws + 36700160);   // 2*4*2048*64 bf16  (2,097,152 B)
  u16* Ob   = (u16*)(ws + 38797312);   // 4096x1024 bf16    (8,388,608 B)
  // total ws use: 47,185,920 B

  k_cast<<<4096, 256, 0, stream>>>(x, xb, 1048576);
  k_transpose_cast<<<dim3(48, 32), dim3(32, 8), 0, stream>>>(wa, waT, 1024, 1536);
  k_transpose_cast<<<dim3(32, 32), dim3(32, 8), 0, stream>>>(wp, wpT, 1024, 1024);
  k_gemm_bt<1><<<dim3(12, 32), 256, 0, stream>>>(xb, waT, qkvb, 4096, 1536, 1024);
  k_rope_rms<<<dim3(4096, 6), 128, 0, stream>>>(qkvb, Qb, Kb, Vb);
  k_attn<<<dim3(32, 32), 256, 0, stream>>>(Qb, Kb, Vb, Ob);
  k_gemm_bt<0><<<dim3(8, 32), 256, 0, stream>>>(Ob, wpT, out, 4096, 1024, 1024);
}

// Round 2
// 185.790 us; speedup vs baseline: 1.3420x; 1.3420x over previous
//
#include <hip/hip_runtime.h>

typedef unsigned short u16;
typedef __attribute__((ext_vector_type(8))) short bf16x8;
typedef __attribute__((ext_vector_type(4))) float f32x4;
typedef __attribute__((ext_vector_type(8))) unsigned short u16x8;
typedef __attribute__((ext_vector_type(4))) unsigned short u16x4;
typedef __attribute__((ext_vector_type(2))) unsigned short u16x2;

// ---- bf16 helpers (RNE) ----
__device__ __forceinline__ u16 f2b(float f) {
  unsigned u = __builtin_bit_cast(unsigned, f);
  unsigned r = (u + 0x7fffu + ((u >> 16) & 1u)) >> 16;
  return (u16)r;
}
__device__ __forceinline__ float b2f(u16 u) {
  return __builtin_bit_cast(float, ((unsigned)u) << 16);
}
__device__ __forceinline__ void gload16(const void* g, void* l) {
  __builtin_amdgcn_global_load_lds(
      (const __attribute__((address_space(1))) unsigned int*)g,
      (__attribute__((address_space(3))) unsigned int*)l, 16, 0, 0);
}

// ---- cast f32 -> bf16, 4 elems/thread ----
__global__ __launch_bounds__(256) void k_cast(const float* __restrict__ in,
                                              u16* __restrict__ out, int n4) {
  int i = blockIdx.x * 256 + threadIdx.x;
  if (i >= n4) return;
  float4 v = ((const float4*)in)[i];
  u16x4 o;
  o.x = f2b(v.x); o.y = f2b(v.y); o.z = f2b(v.z); o.w = f2b(v.w);
  ((u16x4*)out)[i] = o;
}

// ---- transpose + cast: in (M x N) f32 -> out (N x M) bf16 ----
__global__ __launch_bounds__(256) void k_transpose_cast(const float* __restrict__ in,
                                                        u16* __restrict__ out, int M, int N) {
  __shared__ float t[32][33];
  int c0 = blockIdx.x * 32, r0 = blockIdx.y * 32;
  int tx = threadIdx.x, ty = threadIdx.y;  // block (32,8)
  for (int ii = 0; ii < 4; ++ii) {
    int i = ty + ii * 8;
    t[i][tx] = in[(size_t)(r0 + i) * N + c0 + tx];
  }
  __syncthreads();
  for (int ii = 0; ii < 4; ++ii) {
    int i = ty + ii * 8;
    out[(size_t)(c0 + i) * M + r0 + tx] = f2b(t[tx][i]);
  }
}

// ---- V transpose: qkv cols [1280+g*64, +64) -> Vt[b][g][64][2048] (bf16) ----
// grid (64 t-tiles, 2 d-tiles, 8 bg), block (32,8)
__global__ __launch_bounds__(256) void k_vt(const u16* __restrict__ qkv,
                                            u16* __restrict__ Vt) {
  __shared__ u16 t[32][33];
  int bg = blockIdx.z;
  int b = bg >> 2, g = bg & 3;
  int t0 = blockIdx.x * 32, d0 = blockIdx.y * 32;
  int tx = threadIdx.x, ty = threadIdx.y;
  const u16* src = qkv + (size_t)b * 2048 * 1536 + 1280 + g * 64;
  for (int ii = 0; ii < 4; ++ii) {
    int r = ty + ii * 8;
    t[r][tx] = src[(size_t)(t0 + r) * 1536 + d0 + tx];
  }
  __syncthreads();
  u16* dst = Vt + (size_t)bg * 64 * 2048;
  for (int ii = 0; ii < 4; ++ii) {
    int r = ty + ii * 8;
    dst[(size_t)(d0 + r) * 2048 + t0 + tx] = t[tx][r];
  }
}

// ---- GEMM: C[M,N] = A[M,K](bf16,row) * Bt[N,K](bf16,row) ----
template<int OUT_BF16>
__global__ __launch_bounds__(256) void k_gemm_bt(const u16* __restrict__ A,
                                                 const u16* __restrict__ Bt,
                                                 void* __restrict__ Cv,
                                                 int M, int N, int K) {
  __shared__ u16 lA[128 * 32];
  __shared__ u16 lB[128 * 32];
  const int tid = threadIdx.x;
  const int lane = tid & 63, w = tid >> 6;
  const int wr = w >> 1, wc = w & 1;
  const int la = lane & 15, hi = lane >> 4;
  const int bm0 = blockIdx.y * 128, bn0 = blockIdx.x * 128;
  const f32x4 zero = {0.f, 0.f, 0.f, 0.f};
  f32x4 acc[4][4];
#pragma unroll
  for (int m = 0; m < 4; ++m)
#pragma unroll
    for (int n = 0; n < 4; ++n) acc[m][n] = zero;

  const int r0 = tid >> 2;
  const int c8 = (tid & 3) * 8;
  for (int k0 = 0; k0 < K; k0 += 32) {
    gload16(A  + (size_t)(bm0 + r0)      * K + k0 + c8, &lA[tid * 8]);
    gload16(A  + (size_t)(bm0 + r0 + 64) * K + k0 + c8, &lA[(tid + 256) * 8]);
    gload16(Bt + (size_t)(bn0 + r0)      * K + k0 + c8, &lB[tid * 8]);
    gload16(Bt + (size_t)(bn0 + r0 + 64) * K + k0 + c8, &lB[(tid + 256) * 8]);
    __syncthreads();
    bf16x8 af[4], bfr[4];
#pragma unroll
    for (int m = 0; m < 4; ++m)
      af[m] = *(const bf16x8*)&lA[(wr * 64 + m * 16 + la) * 32 + hi * 8];
#pragma unroll
    for (int n = 0; n < 4; ++n)
      bfr[n] = *(const bf16x8*)&lB[(wc * 64 + n * 16 + la) * 32 + hi * 8];
#pragma unroll
    for (int m = 0; m < 4; ++m)
#pragma unroll
      for (int n = 0; n < 4; ++n)
        acc[m][n] = __builtin_amdgcn_mfma_f32_16x16x32_bf16(af[m], bfr[n], acc[m][n], 0, 0, 0);
    __syncthreads();
  }
  float* Cf = (float*)Cv;
  u16*   Cb = (u16*)Cv;
#pragma unroll
  for (int m = 0; m < 4; ++m)
#pragma unroll
    for (int n = 0; n < 4; ++n)
#pragma unroll
      for (int j = 0; j < 4; ++j) {
        int row = bm0 + wr * 64 + m * 16 + hi * 4 + j;
        int col = bn0 + wc * 64 + n * 16 + la;
        float v = acc[m][n][j];
        if (OUT_BF16) Cb[(size_t)row * N + col] = f2b(v);
        else          Cf[(size_t)row * N + col] = v;
      }
}

// ---- RoPE (interleaved pairs) + RMS-norm for Q and K only ----
// grid (B*T, 5), block 128: grp 0..3 = q heads, grp 4 = k heads.
__global__ __launch_bounds__(128) void k_rope_rms(const u16* __restrict__ qkv,
                                                  u16* __restrict__ Qb,
                                                  u16* __restrict__ Kb) {
  const int row = blockIdx.x;        // b*T + t
  const int grp = blockIdx.y;
  const int tid = threadIdx.x;
  const int sub = tid >> 5, i = tid & 31;
  const int b = row >> 11, t = row & 2047;
  int col, kind, head;
  if (grp < 4) { head = grp * 4 + sub; col = head * 64;       kind = 0; }
  else         { head = sub;           col = 1024 + sub * 64; kind = 1; }
  u16x2 xv = *(const u16x2*)(qkv + (size_t)row * 1536 + col + 2 * i);
  float x0 = b2f(xv.x), x1 = b2f(xv.y);
  {
    float inv = expf((float)(2 * i) * -0.14391156831f);  // 10000^(-2i/64)
    float fr = (float)t * inv;
    float s, c;
    sincosf(fr, &s, &c);
    float r0 = x0 * c - x1 * s;
    float r1 = x1 * c + x0 * s;
    x0 = r0; x1 = r1;
  }
  float ss = x0 * x0 + x1 * x1;
#pragma unroll
  for (int off = 16; off >= 1; off >>= 1) ss += __shfl_xor(ss, off, 32);
  float sc = rsqrtf(ss * (1.0f / 64.0f) + 1e-6f);
  u16x2 o;
  o.x = f2b(x0 * sc); o.y = f2b(x1 * sc);
  size_t ob;
  if (kind == 0) ob = ((size_t)((b * 16 + head) * 2048 + t)) * 64 + 2 * i;
  else           ob = ((size_t)((b * 4  + head) * 2048 + t)) * 64 + 2 * i;
  u16* outp = (kind == 0) ? Qb : Kb;
  *(u16x2*)(outp + ob) = o;
}

// ---- causal GQA flash attention, v2 ----
// grid (16 q-tiles of 128 rows, B*NH=32), block 512 (8 waves x 16 q-rows).
// KV tiles of 64. V pre-transposed (Vt[bg][64][2048]). All hot LDS ops are
// b128 at stride 72 u16 (conflict-free pattern: bank-group 4*((r+s)%8)).
__global__ __launch_bounds__(512) void k_attn(const u16* __restrict__ Qb,
                                              const u16* __restrict__ Kb,
                                              const u16* __restrict__ Vtb,
                                              u16* __restrict__ Ob) {
  __shared__ u16 lK[64][72];    // K tile  [kv][d]
  __shared__ u16 lVt[64][72];   // Vt tile [d][kv]
  __shared__ u16 lP[8][16][72]; // per-wave P [q-local][kv]
  const int bh = blockIdx.y;
  const int b = bh >> 4, h = bh & 15, g = h >> 2;
  const int qtile = (int)(gridDim.x - 1 - blockIdx.x);  // heavy first
  const int tid = threadIdx.x;
  const int lane = tid & 63, w = tid >> 6;
  const int la = lane & 15, hi = lane >> 4;
  const int qr0 = qtile * 128 + w * 16;

  const u16* Qg  = Qb  + (size_t)(b * 16 + h) * 2048 * 64;
  const u16* Kg  = Kb  + (size_t)(b * 4 + g) * 2048 * 64;
  const u16* Vtg = Vtb + (size_t)(b * 4 + g) * 64 * 2048;

  bf16x8 qf0, qf1;
  {
    const u16* p = Qg + (size_t)(qr0 + la) * 64 + hi * 8;
    qf0 = *(const bf16x8*)p;
    qf1 = *(const bf16x8*)(p + 32);
  }
  float m_[4] = {-1e30f, -1e30f, -1e30f, -1e30f};
  float l_[4] = {0.f, 0.f, 0.f, 0.f};
  const f32x4 zero = {0.f, 0.f, 0.f, 0.f};
  f32x4 ao[4];
#pragma unroll
  for (int f = 0; f < 4; ++f) ao[f] = zero;

  const int nt = 2 * qtile + 2;
  const int ktmax_w = qr0 >> 6;       // wave's last participating tile
  const int sr = tid >> 3;            // staging row 0..63
  const int ss = (tid & 7) * 8;       // staging col chunk

  u16x8 kreg = *(const u16x8*)(Kg + (size_t)sr * 64 + ss);
  u16x8 vreg = *(const u16x8*)(Vtg + (size_t)sr * 2048 + ss);

  for (int kt = 0; kt < nt; ++kt) {
    __syncthreads();                  // previous tile fully consumed
    *(u16x8*)(&lK[sr][ss])  = kreg;
    *(u16x8*)(&lVt[sr][ss]) = vreg;
    if (kt + 1 < nt) {                // async-stage next tile (T14)
      int kv = (kt + 1) * 64;
      kreg = *(const u16x8*)(Kg + (size_t)(kv + sr) * 64 + ss);
      vreg = *(const u16x8*)(Vtg + (size_t)sr * 2048 + kv + ss);
    }
    __syncthreads();                  // LDS tile ready
    if (kt <= ktmax_w) {
      const int kv0 = kt * 64;
      float p_[4][4];  // [n][j]
#pragma unroll
      for (int n = 0; n < 4; ++n) {
        bf16x8 kb0 = *(const bf16x8*)(&lK[n * 16 + la][hi * 8]);
        bf16x8 kb1 = *(const bf16x8*)(&lK[n * 16 + la][hi * 8 + 32]);
        f32x4 z = zero;
        z = __builtin_amdgcn_mfma_f32_16x16x32_bf16(qf0, kb0, z, 0, 0, 0);
        z = __builtin_amdgcn_mfma_f32_16x16x32_bf16(qf1, kb1, z, 0, 0, 0);
#pragma unroll
        for (int j = 0; j < 4; ++j) p_[n][j] = z[j] * 0.125f;
      }
      if (kt == ktmax_w) {            // diagonal tile: causal mask
#pragma unroll
        for (int n = 0; n < 4; ++n) {
          int colv = kv0 + n * 16 + la;
#pragma unroll
          for (int j = 0; j < 4; ++j) {
            int qrow = qr0 + hi * 4 + j;
            if (colv > qrow) p_[n][j] = -1e30f;
          }
        }
      }
#pragma unroll
      for (int j = 0; j < 4; ++j) {
        float rm = fmaxf(fmaxf(p_[0][j], p_[1][j]), fmaxf(p_[2][j], p_[3][j]));
#pragma unroll
        for (int off = 1; off < 16; off <<= 1) rm = fmaxf(rm, __shfl_xor(rm, off, 16));
        float mn = fmaxf(m_[j], rm);
        float al = __expf(m_[j] - mn);
        float rs = 0.f;
#pragma unroll
        for (int n = 0; n < 4; ++n) {
          float p = __expf(p_[n][j] - mn);
          p_[n][j] = p;
          rs += p;
        }
#pragma unroll
        for (int off = 1; off < 16; off <<= 1) rs += __shfl_xor(rs, off, 16);
        l_[j] = l_[j] * al + rs;
        m_[j] = mn;
#pragma unroll
        for (int f = 0; f < 4; ++f) ao[f][j] *= al;
      }
#pragma unroll
      for (int n = 0; n < 4; ++n)
#pragma unroll
        for (int j = 0; j < 4; ++j)
          lP[w][hi * 4 + j][n * 16 + la] = f2b(p_[n][j]);
      bf16x8 pa0 = *(const bf16x8*)(&lP[w][la][hi * 8]);
      bf16x8 pa1 = *(const bf16x8*)(&lP[w][la][hi * 8 + 32]);
#pragma unroll
      for (int f = 0; f < 4; ++f) {
        bf16x8 v0 = *(const bf16x8*)(&lVt[f * 16 + la][hi * 8]);
        bf16x8 v1 = *(const bf16x8*)(&lVt[f * 16 + la][hi * 8 + 32]);
        ao[f] = __builtin_amdgcn_mfma_f32_16x16x32_bf16(pa0, v0, ao[f], 0, 0, 0);
        ao[f] = __builtin_amdgcn_mfma_f32_16x16x32_bf16(pa1, v1, ao[f], 0, 0, 0);
      }
    }
  }
#pragma unroll
  for (int j = 0; j < 4; ++j) l_[j] = 1.0f / l_[j];
#pragma unroll
  for (int f = 0; f < 4; ++f)
#pragma unroll
    for (int j = 0; j < 4; ++j) {
      int row = qr0 + hi * 4 + j;
      Ob[((size_t)(b * 2048 + row)) * 1024 + h * 64 + f * 16 + la] = f2b(ao[f][j] * l_[j]);
    }
}

extern "C" void kernel_launch(void* const* d_in, const int* in_sizes, int n_in,
                              void* d_out, int out_size, void* d_ws, size_t ws_size,
                              hipStream_t stream) {
  const float* x  = (const float*)d_in[0];   // (2,2048,1024) f32
  const float* wa = (const float*)d_in[1];   // (1024,1536)  f32
  const float* wp = (const float*)d_in[2];   // (1024,1024)  f32
  float* out = (float*)d_out;                // (2,2048,1024) f32
  char* ws = (char*)d_ws;
  u16* xb   = (u16*)(ws + 0);          // 4096x1024 bf16
  u16* waT  = (u16*)(ws + 8388608);    // 1536x1024 bf16
  u16* wpT  = (u16*)(ws + 11534336);   // 1024x1024 bf16
  u16* qkvb = (u16*)(ws + 13631488);   // 4096x1536 bf16
  u16* Qb   = (u16*)(ws + 26214400);   // [2][16][2048][64] bf16
  u16* Kb   = (u16*)(ws + 34603008);   // [2][4][2048][64] bf16
  u16* Vtb  = (u16*)(ws + 36700160);   // [2][4][64][2048] bf16
  u16* Ob   = (u16*)(ws + 38797312);   // 4096x1024 bf16

  k_cast<<<4096, 256, 0, stream>>>(x, xb, 1048576);
  k_transpose_cast<<<dim3(48, 32), dim3(32, 8), 0, stream>>>(wa, waT, 1024, 1536);
  k_transpose_cast<<<dim3(32, 32), dim3(32, 8), 0, stream>>>(wp, wpT, 1024, 1024);
  k_gemm_bt<1><<<dim3(12, 32), 256, 0, stream>>>(xb, waT, qkvb, 4096, 1536, 1024);
  k_rope_rms<<<dim3(4096, 5), 128, 0, stream>>>(qkvb, Qb, Kb);
  k_vt<<<dim3(64, 2, 8), dim3(32, 8), 0, stream>>>(qkvb, Vtb);
  k_attn<<<dim3(16, 32), 512, 0, stream>>>(Qb, Kb, Vtb, Ob);
  k_gemm_bt<0><<<dim3(8, 32), 256, 0, stream>>>(Ob, wpT, out, 4096, 1024, 1024);
}

// Round 3
// 131.375 us; speedup vs baseline: 1.8978x; 1.4142x over previous
//
#include <hip/hip_runtime.h>

typedef unsigned short u16;
typedef __attribute__((ext_vector_type(8))) short bf16x8;
typedef __attribute__((ext_vector_type(4))) float f32x4;
typedef __attribute__((ext_vector_type(8))) unsigned short u16x8;
typedef __attribute__((ext_vector_type(4))) unsigned short u16x4;
typedef __attribute__((ext_vector_type(2))) unsigned short u16x2;

// ---- bf16 helpers (RNE) ----
__device__ __forceinline__ u16 f2b(float f) {
  unsigned u = __builtin_bit_cast(unsigned, f);
  unsigned r = (u + 0x7fffu + ((u >> 16) & 1u)) >> 16;
  return (u16)r;
}
__device__ __forceinline__ float b2f(u16 u) {
  return __builtin_bit_cast(float, ((unsigned)u) << 16);
}
__device__ __forceinline__ void gload16(const void* g, void* l) {
  __builtin_amdgcn_global_load_lds(
      (const __attribute__((address_space(1))) unsigned int*)g,
      (__attribute__((address_space(3))) unsigned int*)l, 16, 0, 0);
}

// ---- cast f32 -> bf16, 4 elems/thread ----
__global__ __launch_bounds__(256) void k_cast(const float* __restrict__ in,
                                              u16* __restrict__ out, int n4) {
  int i = blockIdx.x * 256 + threadIdx.x;
  if (i >= n4) return;
  float4 v = ((const float4*)in)[i];
  u16x4 o;
  o.x = f2b(v.x); o.y = f2b(v.y); o.z = f2b(v.z); o.w = f2b(v.w);
  ((u16x4*)out)[i] = o;
}

// ---- transpose + cast: in (M x N) f32 -> out (N x M) bf16 ----
__global__ __launch_bounds__(256) void k_transpose_cast(const float* __restrict__ in,
                                                        u16* __restrict__ out, int M, int N) {
  __shared__ float t[32][33];
  int c0 = blockIdx.x * 32, r0 = blockIdx.y * 32;
  int tx = threadIdx.x, ty = threadIdx.y;  // block (32,8)
  for (int ii = 0; ii < 4; ++ii) {
    int i = ty + ii * 8;
    t[i][tx] = in[(size_t)(r0 + i) * N + c0 + tx];
  }
  __syncthreads();
  for (int ii = 0; ii < 4; ++ii) {
    int i = ty + ii * 8;
    out[(size_t)(c0 + i) * M + r0 + tx] = f2b(t[tx][i]);
  }
}

// ---- V transpose: qkv cols [1280+g*64, +64) -> Vt[b][g][64][2048] (bf16) ----
__global__ __launch_bounds__(256) void k_vt(const u16* __restrict__ qkv,
                                            u16* __restrict__ Vt) {
  __shared__ u16 t[32][33];
  int bg = blockIdx.z;
  int b = bg >> 2, g = bg & 3;
  int t0 = blockIdx.x * 32, d0 = blockIdx.y * 32;
  int tx = threadIdx.x, ty = threadIdx.y;
  const u16* src = qkv + (size_t)b * 2048 * 1536 + 1280 + g * 64;
  for (int ii = 0; ii < 4; ++ii) {
    int r = ty + ii * 8;
    t[r][tx] = src[(size_t)(t0 + r) * 1536 + d0 + tx];
  }
  __syncthreads();
  u16* dst = Vt + (size_t)bg * 64 * 2048;
  for (int ii = 0; ii < 4; ++ii) {
    int r = ty + ii * 8;
    dst[(size_t)(d0 + r) * 2048 + t0 + tx] = t[tx][r];
  }
}

// ---- GEMM: C[M,N] = A[M,K](bf16,row) * Bt[N,K](bf16,row) ----
template<int OUT_BF16>
__global__ __launch_bounds__(256) void k_gemm_bt(const u16* __restrict__ A,
                                                 const u16* __restrict__ Bt,
                                                 void* __restrict__ Cv,
                                                 int M, int N, int K) {
  __shared__ u16 lA[128 * 32];
  __shared__ u16 lB[128 * 32];
  const int tid = threadIdx.x;
  const int lane = tid & 63, w = tid >> 6;
  const int wr = w >> 1, wc = w & 1;
  const int la = lane & 15, hi = lane >> 4;
  const int bm0 = blockIdx.y * 128, bn0 = blockIdx.x * 128;
  const f32x4 zero = {0.f, 0.f, 0.f, 0.f};
  f32x4 acc[4][4];
#pragma unroll
  for (int m = 0; m < 4; ++m)
#pragma unroll
    for (int n = 0; n < 4; ++n) acc[m][n] = zero;

  const int r0 = tid >> 2;
  const int c8 = (tid & 3) * 8;
  for (int k0 = 0; k0 < K; k0 += 32) {
    gload16(A  + (size_t)(bm0 + r0)      * K + k0 + c8, &lA[tid * 8]);
    gload16(A  + (size_t)(bm0 + r0 + 64) * K + k0 + c8, &lA[(tid + 256) * 8]);
    gload16(Bt + (size_t)(bn0 + r0)      * K + k0 + c8, &lB[tid * 8]);
    gload16(Bt + (size_t)(bn0 + r0 + 64) * K + k0 + c8, &lB[(tid + 256) * 8]);
    __syncthreads();
    bf16x8 af[4], bfr[4];
#pragma unroll
    for (int m = 0; m < 4; ++m)
      af[m] = *(const bf16x8*)&lA[(wr * 64 + m * 16 + la) * 32 + hi * 8];
#pragma unroll
    for (int n = 0; n < 4; ++n)
      bfr[n] = *(const bf16x8*)&lB[(wc * 64 + n * 16 + la) * 32 + hi * 8];
#pragma unroll
    for (int m = 0; m < 4; ++m)
#pragma unroll
      for (int n = 0; n < 4; ++n)
        acc[m][n] = __builtin_amdgcn_mfma_f32_16x16x32_bf16(af[m], bfr[n], acc[m][n], 0, 0, 0);
    __syncthreads();
  }
  float* Cf = (float*)Cv;
  u16*   Cb = (u16*)Cv;
#pragma unroll
  for (int m = 0; m < 4; ++m)
#pragma unroll
    for (int n = 0; n < 4; ++n)
#pragma unroll
      for (int j = 0; j < 4; ++j) {
        int row = bm0 + wr * 64 + m * 16 + hi * 4 + j;
        int col = bn0 + wc * 64 + n * 16 + la;
        float v = acc[m][n][j];
        if (OUT_BF16) Cb[(size_t)row * N + col] = f2b(v);
        else          Cf[(size_t)row * N + col] = v;
      }
}

// ---- RoPE cos/sin table: tab[t][i] = (cos, sin) of t * 10000^(-2i/64) ----
__global__ __launch_bounds__(64) void k_rope_tab(float2* __restrict__ tab) {
  int t = blockIdx.x * 2 + (threadIdx.x >> 5);
  int i = threadIdx.x & 31;
  float inv = expf((float)(2 * i) * -0.14391156831f);
  float fr = (float)t * inv;
  float s, c;
  sincosf(fr, &s, &c);
  tab[t * 32 + i] = make_float2(c, s);
}

// ---- RoPE (interleaved pairs) + RMS-norm for Q and K only ----
__global__ __launch_bounds__(128) void k_rope_rms(const u16* __restrict__ qkv,
                                                  const float2* __restrict__ tab,
                                                  u16* __restrict__ Qb,
                                                  u16* __restrict__ Kb) {
  const int row = blockIdx.x;        // b*T + t
  const int grp = blockIdx.y;
  const int tid = threadIdx.x;
  const int sub = tid >> 5, i = tid & 31;
  const int b = row >> 11, t = row & 2047;
  int col, kind, head;
  if (grp < 4) { head = grp * 4 + sub; col = head * 64;       kind = 0; }
  else         { head = sub;           col = 1024 + sub * 64; kind = 1; }
  u16x2 xv = *(const u16x2*)(qkv + (size_t)row * 1536 + col + 2 * i);
  float x0 = b2f(xv.x), x1 = b2f(xv.y);
  float2 cs = tab[t * 32 + i];
  {
    float r0 = x0 * cs.x - x1 * cs.y;
    float r1 = x1 * cs.x + x0 * cs.y;
    x0 = r0; x1 = r1;
  }
  float ss = x0 * x0 + x1 * x1;
#pragma unroll
  for (int off = 16; off >= 1; off >>= 1) ss += __shfl_xor(ss, off, 32);
  float sc = rsqrtf(ss * (1.0f / 64.0f) + 1e-6f);
  u16x2 o;
  o.x = f2b(x0 * sc); o.y = f2b(x1 * sc);
  size_t ob;
  if (kind == 0) ob = ((size_t)((b * 16 + head) * 2048 + t)) * 64 + 2 * i;
  else           ob = ((size_t)((b * 4  + head) * 2048 + t)) * 64 + 2 * i;
  u16* outp = (kind == 0) ? Qb : Kb;
  *(u16x2*)(outp + ob) = o;
}

// ---- causal GQA flash attention, v3 (swapped QK^T, in-lane softmax) ----
// grid (32 bh, 32 qtiles of 64 rows), block 256 (4 waves x 16 q-rows).
// Heavy qtiles dispatch first (bh fastest). KV tiles of 64.
// S^T = mfma(K, Q): lane holds P[kv = n*16+hi*4+j][q = la] -> softmax row is
// 16 in-lane values + 2 shfl_xor across the 4 hi-lanes.
__global__ __launch_bounds__(256) void k_attn(const u16* __restrict__ Qb,
                                              const u16* __restrict__ Kb,
                                              const u16* __restrict__ Vtb,
                                              u16* __restrict__ Ob) {
  __shared__ u16 lK[64][72];    // K tile  [kv][d]
  __shared__ u16 lVt[64][72];   // Vt tile [d][kv]
  __shared__ u16 lP[4][16][72]; // per-wave P [q-local][kv]
  const int bh = blockIdx.x;
  const int b = bh >> 4, h = bh & 15, g = h >> 2;
  const int qtile = (int)(gridDim.y - 1 - blockIdx.y);  // heavy first
  const int tid = threadIdx.x;
  const int lane = tid & 63, w = tid >> 6;
  const int la = lane & 15, hi = lane >> 4;
  const int qr0 = qtile * 64 + w * 16;

  const u16* Qg  = Qb  + (size_t)(b * 16 + h) * 2048 * 64;
  const u16* Kg  = Kb  + (size_t)(b * 4 + g) * 2048 * 64;
  const u16* Vtg = Vtb + (size_t)(b * 4 + g) * 64 * 2048;

  bf16x8 qf0, qf1;
  {
    const u16* p = Qg + (size_t)(qr0 + la) * 64 + hi * 8;
    qf0 = *(const bf16x8*)p;
    qf1 = *(const bf16x8*)(p + 32);
  }
  float m_ = -1e30f, l_ = 0.f;
  const f32x4 zero = {0.f, 0.f, 0.f, 0.f};
  f32x4 ao[4];
#pragma unroll
  for (int f = 0; f < 4; ++f) ao[f] = zero;

  const int nt = qtile + 1;
  const int sr = tid >> 3;            // staging row 0..31 (+32)
  const int ss = (tid & 7) * 8;       // staging col chunk

  u16x8 kreg0 = *(const u16x8*)(Kg  + (size_t)sr * 64 + ss);
  u16x8 kreg1 = *(const u16x8*)(Kg  + (size_t)(sr + 32) * 64 + ss);
  u16x8 vreg0 = *(const u16x8*)(Vtg + (size_t)sr * 2048 + ss);
  u16x8 vreg1 = *(const u16x8*)(Vtg + (size_t)(sr + 32) * 2048 + ss);

  for (int kt = 0; kt < nt; ++kt) {
    __syncthreads();                  // previous tile fully consumed
    *(u16x8*)(&lK[sr][ss])       = kreg0;
    *(u16x8*)(&lK[sr + 32][ss])  = kreg1;
    *(u16x8*)(&lVt[sr][ss])      = vreg0;
    *(u16x8*)(&lVt[sr + 32][ss]) = vreg1;
    if (kt + 1 < nt) {                // async-stage next tile
      int kv = (kt + 1) * 64;
      kreg0 = *(const u16x8*)(Kg  + (size_t)(kv + sr) * 64 + ss);
      kreg1 = *(const u16x8*)(Kg  + (size_t)(kv + sr + 32) * 64 + ss);
      vreg0 = *(const u16x8*)(Vtg + (size_t)sr * 2048 + kv + ss);
      vreg1 = *(const u16x8*)(Vtg + (size_t)(sr + 32) * 2048 + kv + ss);
    }
    __syncthreads();                  // LDS tile ready

    // S^T = K Q^T for this wave: lane -> q=la, kv = n*16 + hi*4 + j
    float p_[4][4];
    __builtin_amdgcn_s_setprio(1);
#pragma unroll
    for (int n = 0; n < 4; ++n) {
      bf16x8 kb0 = *(const bf16x8*)(&lK[n * 16 + la][hi * 8]);
      bf16x8 kb1 = *(const bf16x8*)(&lK[n * 16 + la][hi * 8 + 32]);
      f32x4 z = zero;
      z = __builtin_amdgcn_mfma_f32_16x16x32_bf16(kb0, qf0, z, 0, 0, 0);
      z = __builtin_amdgcn_mfma_f32_16x16x32_bf16(kb1, qf1, z, 0, 0, 0);
#pragma unroll
      for (int j = 0; j < 4; ++j) p_[n][j] = z[j] * 0.125f;
    }
    __builtin_amdgcn_s_setprio(0);
    if (kt == nt - 1) {               // diagonal tile: causal mask
#pragma unroll
      for (int n = 0; n < 4; ++n)
#pragma unroll
        for (int j = 0; j < 4; ++j)
          if (n * 16 + hi * 4 + j > w * 16 + la) p_[n][j] = -1e30f;
    }
    // online softmax: row q=la, 16 in-lane values + 2 shfls
    float rm = p_[0][0];
#pragma unroll
    for (int n = 0; n < 4; ++n)
#pragma unroll
      for (int j = 0; j < 4; ++j) rm = fmaxf(rm, p_[n][j]);
    rm = fmaxf(rm, __shfl_xor(rm, 16, 64));
    rm = fmaxf(rm, __shfl_xor(rm, 32, 64));
    float al = 1.0f;
    int rescale = !__all(rm - m_ <= 8.0f);
    if (rescale) {                    // T13 defer-max
      float mn = fmaxf(m_, rm);
      al = __expf(m_ - mn);
      m_ = mn;
    }
    float rs = 0.f;
#pragma unroll
    for (int n = 0; n < 4; ++n)
#pragma unroll
      for (int j = 0; j < 4; ++j) {
        float p = __expf(p_[n][j] - m_);
        p_[n][j] = p;
        rs += p;
      }
    rs += __shfl_xor(rs, 16, 64);
    rs += __shfl_xor(rs, 32, 64);
    l_ = l_ * al + rs;
    if (rescale) {
#pragma unroll
      for (int j = 0; j < 4; ++j) {
        float alj = __shfl(al, 4 * hi + j, 64);
#pragma unroll
        for (int f = 0; f < 4; ++f) ao[f][j] *= alj;
      }
    }
    // pack P -> bf16, vector store to per-wave LDS slice (no barrier needed)
#pragma unroll
    for (int n = 0; n < 4; ++n) {
      unsigned w0, w1;
      asm("v_cvt_pk_bf16_f32 %0, %1, %2" : "=v"(w0) : "v"(p_[n][0]), "v"(p_[n][1]));
      asm("v_cvt_pk_bf16_f32 %0, %1, %2" : "=v"(w1) : "v"(p_[n][2]), "v"(p_[n][3]));
      uint2 pw; pw.x = w0; pw.y = w1;
      *(uint2*)(&lP[w][la][n * 16 + hi * 4]) = pw;
    }
    bf16x8 pa0 = *(const bf16x8*)(&lP[w][la][hi * 8]);
    bf16x8 pa1 = *(const bf16x8*)(&lP[w][la][hi * 8 + 32]);
    __builtin_amdgcn_s_setprio(1);
#pragma unroll
    for (int f = 0; f < 4; ++f) {
      bf16x8 v0 = *(const bf16x8*)(&lVt[f * 16 + la][hi * 8]);
      bf16x8 v1 = *(const bf16x8*)(&lVt[f * 16 + la][hi * 8 + 32]);
      ao[f] = __builtin_amdgcn_mfma_f32_16x16x32_bf16(pa0, v0, ao[f], 0, 0, 0);
      ao[f] = __builtin_amdgcn_mfma_f32_16x16x32_bf16(pa1, v1, ao[f], 0, 0, 0);
    }
    __builtin_amdgcn_s_setprio(0);
  }
  // epilogue: O rows q = hi*4+j, l_ lives on lane q -> broadcast
  float linv[4];
#pragma unroll
  for (int j = 0; j < 4; ++j) linv[j] = 1.0f / __shfl(l_, 4 * hi + j, 64);
#pragma unroll
  for (int f = 0; f < 4; ++f)
#pragma unroll
    for (int j = 0; j < 4; ++j) {
      int row = qr0 + hi * 4 + j;
      Ob[((size_t)(b * 2048 + row)) * 1024 + h * 64 + f * 16 + la] = f2b(ao[f][j] * linv[j]);
    }
}

extern "C" void kernel_launch(void* const* d_in, const int* in_sizes, int n_in,
                              void* d_out, int out_size, void* d_ws, size_t ws_size,
                              hipStream_t stream) {
  const float* x  = (const float*)d_in[0];   // (2,2048,1024) f32
  const float* wa = (const float*)d_in[1];   // (1024,1536)  f32
  const float* wp = (const float*)d_in[2];   // (1024,1024)  f32
  float* out = (float*)d_out;                // (2,2048,1024) f32
  char* ws = (char*)d_ws;
  u16* xb    = (u16*)(ws + 0);          // 4096x1024 bf16
  u16* waT   = (u16*)(ws + 8388608);    // 1536x1024 bf16
  u16* wpT   = (u16*)(ws + 11534336);   // 1024x1024 bf16
  u16* qkvb  = (u16*)(ws + 13631488);   // 4096x1536 bf16
  u16* Qb    = (u16*)(ws + 26214400);   // [2][16][2048][64] bf16
  u16* Kb    = (u16*)(ws + 34603008);   // [2][4][2048][64] bf16
  u16* Vtb   = (u16*)(ws + 36700160);   // [2][4][64][2048] bf16
  u16* Ob    = (u16*)(ws + 38797312);   // 4096x1024 bf16
  float2* rt = (float2*)(ws + 47185920); // 2048x32 float2 (512KB)

  k_rope_tab<<<1024, 64, 0, stream>>>(rt);
  k_cast<<<4096, 256, 0, stream>>>(x, xb, 1048576);
  k_transpose_cast<<<dim3(48, 32), dim3(32, 8), 0, stream>>>(wa, waT, 1024, 1536);
  k_transpose_cast<<<dim3(32, 32), dim3(32, 8), 0, stream>>>(wp, wpT, 1024, 1024);
  k_gemm_bt<1><<<dim3(12, 32), 256, 0, stream>>>(xb, waT, qkvb, 4096, 1536, 1024);
  k_rope_rms<<<dim3(4096, 5), 128, 0, stream>>>(qkvb, rt, Qb, Kb);
  k_vt<<<dim3(64, 2, 8), dim3(32, 8), 0, stream>>>(qkvb, Vtb);
  k_attn<<<dim3(32, 32), 256, 0, stream>>>(Qb, Kb, Vtb, Ob);
  k_gemm_bt<0><<<dim3(8, 32), 256, 0, stream>>>(Ob, wpT, out, 4096, 1024, 1024);
}

// Round 4
// 124.796 us; speedup vs baseline: 1.9979x; 1.0527x over previous
//
#include <hip/hip_runtime.h>

typedef unsigned short u16;
typedef __attribute__((ext_vector_type(8))) short bf16x8;
typedef __attribute__((ext_vector_type(4))) float f32x4;
typedef __attribute__((ext_vector_type(8))) unsigned short u16x8;
typedef __attribute__((ext_vector_type(4))) unsigned short u16x4;
typedef __attribute__((ext_vector_type(2))) unsigned short u16x2;

// ---- bf16 helpers (RNE) ----
__device__ __forceinline__ u16 f2b(float f) {
  unsigned u = __builtin_bit_cast(unsigned, f);
  unsigned r = (u + 0x7fffu + ((u >> 16) & 1u)) >> 16;
  return (u16)r;
}
__device__ __forceinline__ float b2f(u16 u) {
  return __builtin_bit_cast(float, ((unsigned)u) << 16);
}
__device__ __forceinline__ void gload16(const void* g, void* l) {
  __builtin_amdgcn_global_load_lds(
      (const __attribute__((address_space(1))) unsigned int*)g,
      (__attribute__((address_space(3))) unsigned int*)l, 16, 0, 0);
}

// ---- cast f32 -> bf16, 4 elems/thread ----
__global__ __launch_bounds__(256) void k_cast(const float* __restrict__ in,
                                              u16* __restrict__ out, int n4) {
  int i = blockIdx.x * 256 + threadIdx.x;
  if (i >= n4) return;
  float4 v = ((const float4*)in)[i];
  u16x4 o;
  o.x = f2b(v.x); o.y = f2b(v.y); o.z = f2b(v.z); o.w = f2b(v.w);
  ((u16x4*)out)[i] = o;
}

// ---- transpose + cast: in (M x N) f32 -> out (N x M) bf16 ----
__global__ __launch_bounds__(256) void k_transpose_cast(const float* __restrict__ in,
                                                        u16* __restrict__ out, int M, int N) {
  __shared__ float t[32][33];
  int c0 = blockIdx.x * 32, r0 = blockIdx.y * 32;
  int tx = threadIdx.x, ty = threadIdx.y;  // block (32,8)
  for (int ii = 0; ii < 4; ++ii) {
    int i = ty + ii * 8;
    t[i][tx] = in[(size_t)(r0 + i) * N + c0 + tx];
  }
  __syncthreads();
  for (int ii = 0; ii < 4; ++ii) {
    int i = ty + ii * 8;
    out[(size_t)(c0 + i) * M + r0 + tx] = f2b(t[tx][i]);
  }
}

// ---- V transpose: qkv cols [1280+g*64, +64) -> Vt[b][g][64][2048] (bf16) ----
__global__ __launch_bounds__(256) void k_vt(const u16* __restrict__ qkv,
                                            u16* __restrict__ Vt) {
  __shared__ u16 t[32][33];
  int bg = blockIdx.z;
  int b = bg >> 2, g = bg & 3;
  int t0 = blockIdx.x * 32, d0 = blockIdx.y * 32;
  int tx = threadIdx.x, ty = threadIdx.y;
  const u16* src = qkv + (size_t)b * 2048 * 1536 + 1280 + g * 64;
  for (int ii = 0; ii < 4; ++ii) {
    int r = ty + ii * 8;
    t[r][tx] = src[(size_t)(t0 + r) * 1536 + d0 + tx];
  }
  __syncthreads();
  u16* dst = Vt + (size_t)bg * 64 * 2048;
  for (int ii = 0; ii < 4; ++ii) {
    int r = ty + ii * 8;
    dst[(size_t)(d0 + r) * 2048 + t0 + tx] = t[tx][r];
  }
}

// ---- GEMM: C[M,N] = A[M,K](bf16,row) * Bt[N,K](bf16,row) ----
template<int OUT_BF16>
__global__ __launch_bounds__(256) void k_gemm_bt(const u16* __restrict__ A,
                                                 const u16* __restrict__ Bt,
                                                 void* __restrict__ Cv,
                                                 int M, int N, int K) {
  __shared__ u16 lA[128 * 32];
  __shared__ u16 lB[128 * 32];
  const int tid = threadIdx.x;
  const int lane = tid & 63, w = tid >> 6;
  const int wr = w >> 1, wc = w & 1;
  const int la = lane & 15, hi = lane >> 4;
  const int bm0 = blockIdx.y * 128, bn0 = blockIdx.x * 128;
  const f32x4 zero = {0.f, 0.f, 0.f, 0.f};
  f32x4 acc[4][4];
#pragma unroll
  for (int m = 0; m < 4; ++m)
#pragma unroll
    for (int n = 0; n < 4; ++n) acc[m][n] = zero;

  const int r0 = tid >> 2;
  const int c8 = (tid & 3) * 8;
  for (int k0 = 0; k0 < K; k0 += 32) {
    gload16(A  + (size_t)(bm0 + r0)      * K + k0 + c8, &lA[tid * 8]);
    gload16(A  + (size_t)(bm0 + r0 + 64) * K + k0 + c8, &lA[(tid + 256) * 8]);
    gload16(Bt + (size_t)(bn0 + r0)      * K + k0 + c8, &lB[tid * 8]);
    gload16(Bt + (size_t)(bn0 + r0 + 64) * K + k0 + c8, &lB[(tid + 256) * 8]);
    __syncthreads();
    bf16x8 af[4], bfr[4];
#pragma unroll
    for (int m = 0; m < 4; ++m)
      af[m] = *(const bf16x8*)&lA[(wr * 64 + m * 16 + la) * 32 + hi * 8];
#pragma unroll
    for (int n = 0; n < 4; ++n)
      bfr[n] = *(const bf16x8*)&lB[(wc * 64 + n * 16 + la) * 32 + hi * 8];
#pragma unroll
    for (int m = 0; m < 4; ++m)
#pragma unroll
      for (int n = 0; n < 4; ++n)
        acc[m][n] = __builtin_amdgcn_mfma_f32_16x16x32_bf16(af[m], bfr[n], acc[m][n], 0, 0, 0);
    __syncthreads();
  }
  float* Cf = (float*)Cv;
  u16*   Cb = (u16*)Cv;
#pragma unroll
  for (int m = 0; m < 4; ++m)
#pragma unroll
    for (int n = 0; n < 4; ++n)
#pragma unroll
      for (int j = 0; j < 4; ++j) {
        int row = bm0 + wr * 64 + m * 16 + hi * 4 + j;
        int col = bn0 + wc * 64 + n * 16 + la;
        float v = acc[m][n][j];
        if (OUT_BF16) Cb[(size_t)row * N + col] = f2b(v);
        else          Cf[(size_t)row * N + col] = v;
      }
}

// ---- RoPE cos/sin table: tab[t][i] = (cos, sin) of t * 10000^(-2i/64) ----
__global__ __launch_bounds__(64) void k_rope_tab(float2* __restrict__ tab) {
  int t = blockIdx.x * 2 + (threadIdx.x >> 5);
  int i = threadIdx.x & 31;
  float inv = expf((float)(2 * i) * -0.14391156831f);
  float fr = (float)t * inv;
  float s, c;
  sincosf(fr, &s, &c);
  tab[t * 32 + i] = make_float2(c, s);
}

// ---- RoPE (interleaved pairs) + RMS-norm for Q and K, vectorized ----
// grid (4096), block 192: 20 heads x 8 lanes (8 elems/lane), lanes 160+ idle.
__global__ __launch_bounds__(192) void k_rope_rms(const u16* __restrict__ qkv,
                                                  const float2* __restrict__ tab,
                                                  u16* __restrict__ Qb,
                                                  u16* __restrict__ Kb) {
  const int row = blockIdx.x;        // b*T + t
  const int tid = threadIdx.x;
  if (tid >= 160) return;
  const int hh = tid >> 3, s = tid & 7;
  const int b = row >> 11, t = row & 2047;
  const int col = (hh < 16) ? hh * 64 : 1024 + (hh - 16) * 64;
  u16x8 xv = *(const u16x8*)(qkv + (size_t)row * 1536 + col + s * 8);
  float4 c01 = *(const float4*)(tab + t * 32 + s * 4);
  float4 c23 = *(const float4*)(tab + t * 32 + s * 4 + 2);
  float y[8];
  {
    float x0 = b2f(xv[0]), x1 = b2f(xv[1]);
    y[0] = x0 * c01.x - x1 * c01.y; y[1] = x1 * c01.x + x0 * c01.y;
    x0 = b2f(xv[2]); x1 = b2f(xv[3]);
    y[2] = x0 * c01.z - x1 * c01.w; y[3] = x1 * c01.z + x0 * c01.w;
    x0 = b2f(xv[4]); x1 = b2f(xv[5]);
    y[4] = x0 * c23.x - x1 * c23.y; y[5] = x1 * c23.x + x0 * c23.y;
    x0 = b2f(xv[6]); x1 = b2f(xv[7]);
    y[6] = x0 * c23.z - x1 * c23.w; y[7] = x1 * c23.z + x0 * c23.w;
  }
  float ss = 0.f;
#pragma unroll
  for (int e = 0; e < 8; ++e) ss += y[e] * y[e];
  ss += __shfl_xor(ss, 1, 8);
  ss += __shfl_xor(ss, 2, 8);
  ss += __shfl_xor(ss, 4, 8);
  float sc = rsqrtf(ss * (1.0f / 64.0f) + 1e-6f);
  u16x8 o;
#pragma unroll
  for (int e = 0; e < 8; ++e) o[e] = f2b(y[e] * sc);
  size_t ob;
  u16* outp;
  if (hh < 16) { outp = Qb; ob = ((size_t)((b * 16 + hh) * 2048 + t)) * 64 + s * 8; }
  else         { outp = Kb; ob = ((size_t)((b * 4 + hh - 16) * 2048 + t)) * 64 + s * 8; }
  *(u16x8*)(outp + ob) = o;
}

// ---- causal GQA flash attention, v4 ----
// grid (32 bh, 16 qtile-pairs), block 512 (8 waves). Waves 0-3 own qtile
// 31-p, waves 4-7 own qtile p; both halves share one K/V staging stream.
// Pair batching (p = y<8 ? y : 23-y) makes each CU's 2 resident blocks sum
// to a uniform 49 tile-iters. Softmax in raw-z units with exp2 folding.
__global__ __launch_bounds__(512) void k_attn(const u16* __restrict__ Qb,
                                              const u16* __restrict__ Kb,
                                              const u16* __restrict__ Vtb,
                                              u16* __restrict__ Ob) {
  __shared__ u16 lK[64][72];    // K tile  [kv][d]
  __shared__ u16 lVt[64][72];   // Vt tile [d][kv]
  __shared__ u16 lP[8][16][72]; // per-wave P [q-local][kv]
  const int bh = blockIdx.x;
  const int b = bh >> 4, h = bh & 15, g = h >> 2;
  const int y = blockIdx.y;
  const int p = (y < 8) ? y : 23 - y;   // qtile pair id, heavy batch first
  const int tid = threadIdx.x;
  const int lane = tid & 63, w = tid >> 6;
  const int la = lane & 15, hi = lane >> 4;
  const int wl = w & 3;
  const int qtile = (w < 4) ? (31 - p) : p;
  const int qr0 = qtile * 64 + wl * 16;
  const int nt = 32 - p;               // heavy half's tile count

  const u16* Qg  = Qb  + (size_t)(b * 16 + h) * 2048 * 64;
  const u16* Kg  = Kb  + (size_t)(b * 4 + g) * 2048 * 64;
  const u16* Vtg = Vtb + (size_t)(b * 4 + g) * 64 * 2048;

  bf16x8 qf0, qf1;
  {
    const u16* ptr = Qg + (size_t)(qr0 + la) * 64 + hi * 8;
    qf0 = *(const bf16x8*)ptr;
    qf1 = *(const bf16x8*)(ptr + 32);
  }
  const float C = 0.18033688011f;      // 0.125 * log2(e)
  float m_ = -3e38f, l_ = 0.f;
  const f32x4 zero = {0.f, 0.f, 0.f, 0.f};
  f32x4 ao[4];
#pragma unroll
  for (int f = 0; f < 4; ++f) ao[f] = zero;

  const int sr = tid >> 3;             // staging row 0..63
  const int ss = (tid & 7) * 8;        // staging col chunk

  u16x8 kreg = *(const u16x8*)(Kg  + (size_t)sr * 64 + ss);
  u16x8 vreg = *(const u16x8*)(Vtg + (size_t)sr * 2048 + ss);

  for (int kt = 0; kt < nt; ++kt) {
    __syncthreads();                   // previous tile fully consumed
    *(u16x8*)(&lK[sr][ss])  = kreg;
    *(u16x8*)(&lVt[sr][ss]) = vreg;
    if (kt + 1 < nt) {                 // async-stage next tile
      int kv = (kt + 1) * 64;
      kreg = *(const u16x8*)(Kg  + (size_t)(kv + sr) * 64 + ss);
      vreg = *(const u16x8*)(Vtg + (size_t)sr * 2048 + kv + ss);
    }
    __syncthreads();                   // LDS tile ready
    if (kt <= qtile) {
      // S^T = K Q^T: lane -> q=la, kv = n*16 + hi*4 + j (raw z units)
      float z_[4][4];
      __builtin_amdgcn_s_setprio(1);
#pragma unroll
      for (int n = 0; n < 4; ++n) {
        bf16x8 kb0 = *(const bf16x8*)(&lK[n * 16 + la][hi * 8]);
        bf16x8 kb1 = *(const bf16x8*)(&lK[n * 16 + la][hi * 8 + 32]);
        f32x4 z = zero;
        z = __builtin_amdgcn_mfma_f32_16x16x32_bf16(kb0, qf0, z, 0, 0, 0);
        z = __builtin_amdgcn_mfma_f32_16x16x32_bf16(kb1, qf1, z, 0, 0, 0);
#pragma unroll
        for (int j = 0; j < 4; ++j) z_[n][j] = z[j];
      }
      __builtin_amdgcn_s_setprio(0);
      if (kt == qtile) {               // diagonal tile: causal mask
#pragma unroll
        for (int n = 0; n < 4; ++n)
#pragma unroll
          for (int j = 0; j < 4; ++j)
            if (n * 16 + hi * 4 + j > wl * 16 + la) z_[n][j] = -3e38f;
      }
      // row max (max3-fusable tree), reduce across the 4 hi-copies
      float t0 = fmaxf(fmaxf(z_[0][0], z_[0][1]), fmaxf(z_[0][2], z_[0][3]));
      float t1 = fmaxf(fmaxf(z_[1][0], z_[1][1]), fmaxf(z_[1][2], z_[1][3]));
      float t2 = fmaxf(fmaxf(z_[2][0], z_[2][1]), fmaxf(z_[2][2], z_[2][3]));
      float t3 = fmaxf(fmaxf(z_[3][0], z_[3][1]), fmaxf(z_[3][2], z_[3][3]));
      float rm = fmaxf(fmaxf(t0, t1), fmaxf(t2, t3));
      rm = fmaxf(rm, __shfl_xor(rm, 16, 64));
      rm = fmaxf(rm, __shfl_xor(rm, 32, 64));
      float al = 1.0f;
      if (!__all(rm - m_ <= 64.0f)) {  // T13 defer-max (64 z-units = 8 scaled)
        float mn = fmaxf(m_, rm);
        al = __builtin_amdgcn_exp2f((m_ - mn) * C);
        m_ = mn;
#pragma unroll
        for (int j = 0; j < 4; ++j) {
          float alj = __shfl(al, 4 * hi + j, 64);
#pragma unroll
          for (int f = 0; f < 4; ++f) ao[f][j] *= alj;
        }
      }
      float nmc = m_ * -C;
      float rs = 0.f;
#pragma unroll
      for (int n = 0; n < 4; ++n)
#pragma unroll
        for (int j = 0; j < 4; ++j) {
          float pe = __builtin_amdgcn_exp2f(fmaf(z_[n][j], C, nmc));
          z_[n][j] = pe;
          rs += pe;
        }
      rs += __shfl_xor(rs, 16, 64);
      rs += __shfl_xor(rs, 32, 64);
      l_ = l_ * al + rs;
      // pack P -> bf16, vector store to per-wave LDS slice (in-wave RAW ok)
#pragma unroll
      for (int n = 0; n < 4; ++n) {
        unsigned w0, w1;
        asm("v_cvt_pk_bf16_f32 %0, %1, %2" : "=v"(w0) : "v"(z_[n][0]), "v"(z_[n][1]));
        asm("v_cvt_pk_bf16_f32 %0, %1, %2" : "=v"(w1) : "v"(z_[n][2]), "v"(z_[n][3]));
        uint2 pw; pw.x = w0; pw.y = w1;
        *(uint2*)(&lP[w][la][n * 16 + hi * 4]) = pw;
      }
      bf16x8 pa0 = *(const bf16x8*)(&lP[w][la][hi * 8]);
      bf16x8 pa1 = *(const bf16x8*)(&lP[w][la][hi * 8 + 32]);
      __builtin_amdgcn_s_setprio(1);
#pragma unroll
      for (int f = 0; f < 4; ++f) {
        bf16x8 v0 = *(const bf16x8*)(&lVt[f * 16 + la][hi * 8]);
        bf16x8 v1 = *(const bf16x8*)(&lVt[f * 16 + la][hi * 8 + 32]);
        ao[f] = __builtin_amdgcn_mfma_f32_16x16x32_bf16(pa0, v0, ao[f], 0, 0, 0);
        ao[f] = __builtin_amdgcn_mfma_f32_16x16x32_bf16(pa1, v1, ao[f], 0, 0, 0);
      }
      __builtin_amdgcn_s_setprio(0);
    }
  }
  // epilogue: O rows q = hi*4+j; l_ lives on lane q -> broadcast
  float linv[4];
#pragma unroll
  for (int j = 0; j < 4; ++j) linv[j] = 1.0f / __shfl(l_, 4 * hi + j, 64);
#pragma unroll
  for (int f = 0; f < 4; ++f)
#pragma unroll
    for (int j = 0; j < 4; ++j) {
      int row = qr0 + hi * 4 + j;
      Ob[((size_t)(b * 2048 + row)) * 1024 + h * 64 + f * 16 + la] = f2b(ao[f][j] * linv[j]);
    }
}

extern "C" void kernel_launch(void* const* d_in, const int* in_sizes, int n_in,
                              void* d_out, int out_size, void* d_ws, size_t ws_size,
                              hipStream_t stream) {
  const float* x  = (const float*)d_in[0];   // (2,2048,1024) f32
  const float* wa = (const float*)d_in[1];   // (1024,1536)  f32
  const float* wp = (const float*)d_in[2];   // (1024,1024)  f32
  float* out = (float*)d_out;                // (2,2048,1024) f32
  char* ws = (char*)d_ws;
  u16* xb    = (u16*)(ws + 0);          // 4096x1024 bf16
  u16* waT   = (u16*)(ws + 8388608);    // 1536x1024 bf16
  u16* wpT   = (u16*)(ws + 11534336);   // 1024x1024 bf16
  u16* qkvb  = (u16*)(ws + 13631488);   // 4096x1536 bf16
  u16* Qb    = (u16*)(ws + 26214400);   // [2][16][2048][64] bf16
  u16* Kb    = (u16*)(ws + 34603008);   // [2][4][2048][64] bf16
  u16* Vtb   = (u16*)(ws + 36700160);   // [2][4][64][2048] bf16
  u16* Ob    = (u16*)(ws + 38797312);   // 4096x1024 bf16
  float2* rt = (float2*)(ws + 47185920); // 2048x32 float2 (512KB)

  k_rope_tab<<<1024, 64, 0, stream>>>(rt);
  k_cast<<<4096, 256, 0, stream>>>(x, xb, 1048576);
  k_transpose_cast<<<dim3(48, 32), dim3(32, 8), 0, stream>>>(wa, waT, 1024, 1536);
  k_transpose_cast<<<dim3(32, 32), dim3(32, 8), 0, stream>>>(wp, wpT, 1024, 1024);
  k_gemm_bt<1><<<dim3(12, 32), 256, 0, stream>>>(xb, waT, qkvb, 4096, 1536, 1024);
  k_rope_rms<<<4096, 192, 0, stream>>>(qkvb, rt, Qb, Kb);
  k_vt<<<dim3(64, 2, 8), dim3(32, 8), 0, stream>>>(qkvb, Vtb);
  k_attn<<<dim3(32, 16), 512, 0, stream>>>(Qb, Kb, Vtb, Ob);
  k_gemm_bt<0><<<dim3(8, 32), 256, 0, stream>>>(Ob, wpT, out, 4096, 1024, 1024);
}

// Round 5
// 94.172 us; speedup vs baseline: 2.6476x; 1.3252x over previous
//
#include <hip/hip_runtime.h>

typedef unsigned short u16;
typedef __attribute__((ext_vector_type(8))) short bf16x8;
typedef __attribute__((ext_vector_type(4))) float f32x4;
typedef __attribute__((ext_vector_type(8))) unsigned short u16x8;
typedef __attribute__((ext_vector_type(4))) unsigned short u16x4;
typedef __attribute__((ext_vector_type(2))) unsigned short u16x2;

// ---- bf16 helpers (RNE) ----
__device__ __forceinline__ u16 f2b(float f) {
  unsigned u = __builtin_bit_cast(unsigned, f);
  unsigned r = (u + 0x7fffu + ((u >> 16) & 1u)) >> 16;
  return (u16)r;
}
__device__ __forceinline__ float b2f(u16 u) {
  return __builtin_bit_cast(float, ((unsigned)u) << 16);
}
__device__ __forceinline__ void gload16(const void* g, void* l) {
  __builtin_amdgcn_global_load_lds(
      (const __attribute__((address_space(1))) unsigned int*)g,
      (__attribute__((address_space(3))) unsigned int*)l, 16, 0, 0);
}

// ---- fused prep: x cast (2048) | waT (1536) | wpT (1024) | rope tab (256) ----
__global__ __launch_bounds__(256) void k_prep(const float* __restrict__ x,
                                              const float* __restrict__ wa,
                                              const float* __restrict__ wp,
                                              u16* __restrict__ xb,
                                              u16* __restrict__ waT,
                                              u16* __restrict__ wpT,
                                              float2* __restrict__ tab) {
  __shared__ float t[32][33];
  const int idx = blockIdx.x;
  const int tid = threadIdx.x;
  if (idx < 2048) {                       // cast x -> bf16, 8 elems/thread
    int i = idx * 256 + tid;
    float4 v0 = ((const float4*)x)[i * 2];
    float4 v1 = ((const float4*)x)[i * 2 + 1];
    u16x8 o;
    o[0] = f2b(v0.x); o[1] = f2b(v0.y); o[2] = f2b(v0.z); o[3] = f2b(v0.w);
    o[4] = f2b(v1.x); o[5] = f2b(v1.y); o[6] = f2b(v1.z); o[7] = f2b(v1.w);
    ((u16x8*)xb)[i] = o;
    return;
  }
  const int tx = tid & 31, ty = tid >> 5; // transpose tiles, block as (32,8)
  if (idx < 3584) {                       // waT: (1024 x 1536) -> (1536 x 1024)
    int tt = idx - 2048;
    int c0 = (tt % 48) * 32, r0 = (tt / 48) * 32;
    for (int ii = 0; ii < 4; ++ii)
      t[ty + ii * 8][tx] = wa[(size_t)(r0 + ty + ii * 8) * 1536 + c0 + tx];
    __syncthreads();
    for (int ii = 0; ii < 4; ++ii)
      waT[(size_t)(c0 + ty + ii * 8) * 1024 + r0 + tx] = f2b(t[tx][ty + ii * 8]);
    return;
  }
  if (idx < 4608) {                       // wpT: (1024 x 1024) -> (1024 x 1024)
    int tt = idx - 3584;
    int c0 = (tt & 31) * 32, r0 = (tt >> 5) * 32;
    for (int ii = 0; ii < 4; ++ii)
      t[ty + ii * 8][tx] = wp[(size_t)(r0 + ty + ii * 8) * 1024 + c0 + tx];
    __syncthreads();
    for (int ii = 0; ii < 4; ++ii)
      wpT[(size_t)(c0 + ty + ii * 8) * 1024 + r0 + tx] = f2b(t[tx][ty + ii * 8]);
    return;
  }
  {                                       // rope table
    int e = (idx - 4608) * 256 + tid;     // 65536 entries
    int tt = e >> 5, i = e & 31;
    float inv = expf((float)(2 * i) * -0.14391156831f);
    float fr = (float)tt * inv;
    float s, c;
    sincosf(fr, &s, &c);
    tab[tt * 32 + i] = make_float2(c, s);
  }
}

// ---- GEMM: C[M,N] = A[M,K](bf16,row) * Bt[N,K](bf16,row) ----
// 64x128 tile, BK=64, 4 waves 2x2 (each 32x64), XOR-swizzled LDS (rule 21:
// linear gload_lds dest + pre-swizzled global source + swizzled ds_read).
template<int OUT_BF16>
__global__ __launch_bounds__(256) void k_gemm_bt(const u16* __restrict__ A,
                                                 const u16* __restrict__ Bt,
                                                 void* __restrict__ Cv,
                                                 int M, int N, int K) {
  __shared__ u16 lA[64 * 64];    // [row][8 slots of 8], slot s holds chunk s^(row&7)
  __shared__ u16 lB[128 * 64];
  const int tid = threadIdx.x;
  const int lane = tid & 63, w = tid >> 6;
  const int wr = w >> 1, wc = w & 1;
  const int la = lane & 15, hi = lane >> 4;
  const int bm0 = blockIdx.y * 64, bn0 = blockIdx.x * 128;
  const f32x4 zero = {0.f, 0.f, 0.f, 0.f};
  f32x4 acc[2][4];
#pragma unroll
  for (int m = 0; m < 2; ++m)
#pragma unroll
    for (int n = 0; n < 4; ++n) acc[m][n] = zero;

  const int r = tid >> 3;           // staging row within round (0..31)
  const int s = tid & 7;            // staging slot
  for (int k0 = 0; k0 < K; k0 += 64) {
#pragma unroll
    for (int rr = 0; rr < 2; ++rr) {
      int row = rr * 32 + r;
      gload16(A + (size_t)(bm0 + row) * K + k0 + ((s ^ (row & 7)) << 3),
              &lA[(rr * 256 + tid) * 8]);
    }
#pragma unroll
    for (int rr = 0; rr < 4; ++rr) {
      int row = rr * 32 + r;
      gload16(Bt + (size_t)(bn0 + row) * K + k0 + ((s ^ (row & 7)) << 3),
              &lB[(rr * 256 + tid) * 8]);
    }
    __syncthreads();
#pragma unroll
    for (int kk = 0; kk < 2; ++kk) {
      bf16x8 af[2], bfr[4];
#pragma unroll
      for (int m = 0; m < 2; ++m) {
        int R = wr * 32 + m * 16 + la;
        af[m] = *(const bf16x8*)&lA[R * 64 + (((kk * 4 + hi) ^ (R & 7)) << 3)];
      }
#pragma unroll
      for (int n = 0; n < 4; ++n) {
        int R = wc * 64 + n * 16 + la;
        bfr[n] = *(const bf16x8*)&lB[R * 64 + (((kk * 4 + hi) ^ (R & 7)) << 3)];
      }
#pragma unroll
      for (int m = 0; m < 2; ++m)
#pragma unroll
        for (int n = 0; n < 4; ++n)
          acc[m][n] = __builtin_amdgcn_mfma_f32_16x16x32_bf16(af[m], bfr[n], acc[m][n], 0, 0, 0);
    }
    __syncthreads();
  }
  float* Cf = (float*)Cv;
  u16*   Cb = (u16*)Cv;
#pragma unroll
  for (int m = 0; m < 2; ++m)
#pragma unroll
    for (int n = 0; n < 4; ++n)
#pragma unroll
      for (int j = 0; j < 4; ++j) {
        int row = bm0 + wr * 32 + m * 16 + hi * 4 + j;
        int col = bn0 + wc * 64 + n * 16 + la;
        float v = acc[m][n][j];
        if (OUT_BF16) Cb[(size_t)row * N + col] = f2b(v);
        else          Cf[(size_t)row * N + col] = v;
      }
}

// ---- fused rope_rms (2048 blocks, 2 rows each) + V transpose (1024) ----
// block 320 threads (5 waves).
__global__ __launch_bounds__(320) void k_rvt(const u16* __restrict__ qkv,
                                             const float2* __restrict__ tab,
                                             u16* __restrict__ Qb,
                                             u16* __restrict__ Kb,
                                             u16* __restrict__ Vt) {
  const int idx = blockIdx.x;
  const int tid = threadIdx.x;
  if (idx < 2048) {                     // rope+rms: 2 rows, 160 threads each
    const int half = (tid >= 160);
    const int lt = tid - half * 160;
    const int row = idx * 2 + half;     // b*T + t
    const int hh = lt >> 3, s = lt & 7;
    const int b = row >> 11, t = row & 2047;
    const int col = (hh < 16) ? hh * 64 : 1024 + (hh - 16) * 64;
    u16x8 xv = *(const u16x8*)(qkv + (size_t)row * 1536 + col + s * 8);
    float4 c01 = *(const float4*)(tab + t * 32 + s * 4);
    float4 c23 = *(const float4*)(tab + t * 32 + s * 4 + 2);
    float y[8];
    {
      float x0 = b2f(xv[0]), x1 = b2f(xv[1]);
      y[0] = x0 * c01.x - x1 * c01.y; y[1] = x1 * c01.x + x0 * c01.y;
      x0 = b2f(xv[2]); x1 = b2f(xv[3]);
      y[2] = x0 * c01.z - x1 * c01.w; y[3] = x1 * c01.z + x0 * c01.w;
      x0 = b2f(xv[4]); x1 = b2f(xv[5]);
      y[4] = x0 * c23.x - x1 * c23.y; y[5] = x1 * c23.x + x0 * c23.y;
      x0 = b2f(xv[6]); x1 = b2f(xv[7]);
      y[6] = x0 * c23.z - x1 * c23.w; y[7] = x1 * c23.z + x0 * c23.w;
    }
    float ss = 0.f;
#pragma unroll
    for (int e = 0; e < 8; ++e) ss += y[e] * y[e];
    ss += __shfl_xor(ss, 1, 8);
    ss += __shfl_xor(ss, 2, 8);
    ss += __shfl_xor(ss, 4, 8);
    float sc = rsqrtf(ss * (1.0f / 64.0f) + 1e-6f);
    u16x8 o;
#pragma unroll
    for (int e = 0; e < 8; ++e) o[e] = f2b(y[e] * sc);
    size_t ob;
    u16* outp;
    if (hh < 16) { outp = Qb; ob = ((size_t)((b * 16 + hh) * 2048 + t)) * 64 + s * 8; }
    else         { outp = Kb; ob = ((size_t)((b * 4 + hh - 16) * 2048 + t)) * 64 + s * 8; }
    *(u16x8*)(outp + ob) = o;
    return;
  }
  // V transpose: 1024 tile-blocks, threads 0..255 as (32,8)
  __shared__ u16 t[32][33];
  if (tid >= 256) return;
  const int ii2 = idx - 2048;
  const int bg = ii2 >> 7;              // 0..7
  const int b = bg >> 2, g = bg & 3;
  const int t0 = (ii2 & 63) * 32, d0 = ((ii2 >> 6) & 1) * 32;
  const int tx = tid & 31, ty = tid >> 5;
  const u16* src = qkv + (size_t)b * 2048 * 1536 + 1280 + g * 64;
  for (int ii = 0; ii < 4; ++ii)
    t[ty + ii * 8][tx] = src[(size_t)(t0 + ty + ii * 8) * 1536 + d0 + tx];
  __syncthreads();
  u16* dst = Vt + (size_t)bg * 64 * 2048;
  for (int ii = 0; ii < 4; ++ii)
    dst[(size_t)(d0 + ty + ii * 8) * 2048 + t0 + tx] = t[tx][ty + ii * 8];
}

// ---- causal GQA flash attention, v4 (unchanged from round 4) ----
__global__ __launch_bounds__(512) void k_attn(const u16* __restrict__ Qb,
                                              const u16* __restrict__ Kb,
                                              const u16* __restrict__ Vtb,
                                              u16* __restrict__ Ob) {
  __shared__ u16 lK[64][72];    // K tile  [kv][d]
  __shared__ u16 lVt[64][72];   // Vt tile [d][kv]
  __shared__ u16 lP[8][16][72]; // per-wave P [q-local][kv]
  const int bh = blockIdx.x;
  const int b = bh >> 4, h = bh & 15, g = h >> 2;
  const int y = blockIdx.y;
  const int p = (y < 8) ? y : 23 - y;   // qtile pair id, heavy batch first
  const int tid = threadIdx.x;
  const int lane = tid & 63, w = tid >> 6;
  const int la = lane & 15, hi = lane >> 4;
  const int wl = w & 3;
  const int qtile = (w < 4) ? (31 - p) : p;
  const int qr0 = qtile * 64 + wl * 16;
  const int nt = 32 - p;               // heavy half's tile count

  const u16* Qg  = Qb  + (size_t)(b * 16 + h) * 2048 * 64;
  const u16* Kg  = Kb  + (size_t)(b * 4 + g) * 2048 * 64;
  const u16* Vtg = Vtb + (size_t)(b * 4 + g) * 64 * 2048;

  bf16x8 qf0, qf1;
  {
    const u16* ptr = Qg + (size_t)(qr0 + la) * 64 + hi * 8;
    qf0 = *(const bf16x8*)ptr;
    qf1 = *(const bf16x8*)(ptr + 32);
  }
  const float C = 0.18033688011f;      // 0.125 * log2(e)
  float m_ = -3e38f, l_ = 0.f;
  const f32x4 zero = {0.f, 0.f, 0.f, 0.f};
  f32x4 ao[4];
#pragma unroll
  for (int f = 0; f < 4; ++f) ao[f] = zero;

  const int sr = tid >> 3;             // staging row 0..63
  const int ss = (tid & 7) * 8;        // staging col chunk

  u16x8 kreg = *(const u16x8*)(Kg  + (size_t)sr * 64 + ss);
  u16x8 vreg = *(const u16x8*)(Vtg + (size_t)sr * 2048 + ss);

  for (int kt = 0; kt < nt; ++kt) {
    __syncthreads();
    *(u16x8*)(&lK[sr][ss])  = kreg;
    *(u16x8*)(&lVt[sr][ss]) = vreg;
    if (kt + 1 < nt) {                 // async-stage next tile
      int kv = (kt + 1) * 64;
      kreg = *(const u16x8*)(Kg  + (size_t)(kv + sr) * 64 + ss);
      vreg = *(const u16x8*)(Vtg + (size_t)sr * 2048 + kv + ss);
    }
    __syncthreads();
    if (kt <= qtile) {
      float z_[4][4];
      __builtin_amdgcn_s_setprio(1);
#pragma unroll
      for (int n = 0; n < 4; ++n) {
        bf16x8 kb0 = *(const bf16x8*)(&lK[n * 16 + la][hi * 8]);
        bf16x8 kb1 = *(const bf16x8*)(&lK[n * 16 + la][hi * 8 + 32]);
        f32x4 z = zero;
        z = __builtin_amdgcn_mfma_f32_16x16x32_bf16(kb0, qf0, z, 0, 0, 0);
        z = __builtin_amdgcn_mfma_f32_16x16x32_bf16(kb1, qf1, z, 0, 0, 0);
#pragma unroll
        for (int j = 0; j < 4; ++j) z_[n][j] = z[j];
      }
      __builtin_amdgcn_s_setprio(0);
      if (kt == qtile) {
#pragma unroll
        for (int n = 0; n < 4; ++n)
#pragma unroll
          for (int j = 0; j < 4; ++j)
            if (n * 16 + hi * 4 + j > wl * 16 + la) z_[n][j] = -3e38f;
      }
      float t0 = fmaxf(fmaxf(z_[0][0], z_[0][1]), fmaxf(z_[0][2], z_[0][3]));
      float t1 = fmaxf(fmaxf(z_[1][0], z_[1][1]), fmaxf(z_[1][2], z_[1][3]));
      float t2 = fmaxf(fmaxf(z_[2][0], z_[2][1]), fmaxf(z_[2][2], z_[2][3]));
      float t3 = fmaxf(fmaxf(z_[3][0], z_[3][1]), fmaxf(z_[3][2], z_[3][3]));
      float rm = fmaxf(fmaxf(t0, t1), fmaxf(t2, t3));
      rm = fmaxf(rm, __shfl_xor(rm, 16, 64));
      rm = fmaxf(rm, __shfl_xor(rm, 32, 64));
      float al = 1.0f;
      if (!__all(rm - m_ <= 64.0f)) {  // T13 defer-max
        float mn = fmaxf(m_, rm);
        al = __builtin_amdgcn_exp2f((m_ - mn) * C);
        m_ = mn;
#pragma unroll
        for (int j = 0; j < 4; ++j) {
          float alj = __shfl(al, 4 * hi + j, 64);
#pragma unroll
          for (int f = 0; f < 4; ++f) ao[f][j] *= alj;
        }
      }
      float nmc = m_ * -C;
      float rs = 0.f;
#pragma unroll
      for (int n = 0; n < 4; ++n)
#pragma unroll
        for (int j = 0; j < 4; ++j) {
          float pe = __builtin_amdgcn_exp2f(fmaf(z_[n][j], C, nmc));
          z_[n][j] = pe;
          rs += pe;
        }
      rs += __shfl_xor(rs, 16, 64);
      rs += __shfl_xor(rs, 32, 64);
      l_ = l_ * al + rs;
#pragma unroll
      for (int n = 0; n < 4; ++n) {
        unsigned w0, w1;
        asm("v_cvt_pk_bf16_f32 %0, %1, %2" : "=v"(w0) : "v"(z_[n][0]), "v"(z_[n][1]));
        asm("v_cvt_pk_bf16_f32 %0, %1, %2" : "=v"(w1) : "v"(z_[n][2]), "v"(z_[n][3]));
        uint2 pw; pw.x = w0; pw.y = w1;
        *(uint2*)(&lP[w][la][n * 16 + hi * 4]) = pw;
      }
      bf16x8 pa0 = *(const bf16x8*)(&lP[w][la][hi * 8]);
      bf16x8 pa1 = *(const bf16x8*)(&lP[w][la][hi * 8 + 32]);
      __builtin_amdgcn_s_setprio(1);
#pragma unroll
      for (int f = 0; f < 4; ++f) {
        bf16x8 v0 = *(const bf16x8*)(&lVt[f * 16 + la][hi * 8]);
        bf16x8 v1 = *(const bf16x8*)(&lVt[f * 16 + la][hi * 8 + 32]);
        ao[f] = __builtin_amdgcn_mfma_f32_16x16x32_bf16(pa0, v0, ao[f], 0, 0, 0);
        ao[f] = __builtin_amdgcn_mfma_f32_16x16x32_bf16(pa1, v1, ao[f], 0, 0, 0);
      }
      __builtin_amdgcn_s_setprio(0);
    }
  }
  float linv[4];
#pragma unroll
  for (int j = 0; j < 4; ++j) linv[j] = 1.0f / __shfl(l_, 4 * hi + j, 64);
#pragma unroll
  for (int f = 0; f < 4; ++f)
#pragma unroll
    for (int j = 0; j < 4; ++j) {
      int row = qr0 + hi * 4 + j;
      Ob[((size_t)(b * 2048 + row)) * 1024 + h * 64 + f * 16 + la] = f2b(ao[f][j] * linv[j]);
    }
}

extern "C" void kernel_launch(void* const* d_in, const int* in_sizes, int n_in,
                              void* d_out, int out_size, void* d_ws, size_t ws_size,
                              hipStream_t stream) {
  const float* x  = (const float*)d_in[0];   // (2,2048,1024) f32
  const float* wa = (const float*)d_in[1];   // (1024,1536)  f32
  const float* wp = (const float*)d_in[2];   // (1024,1024)  f32
  float* out = (float*)d_out;                // (2,2048,1024) f32
  char* ws = (char*)d_ws;
  u16* xb    = (u16*)(ws + 0);          // 4096x1024 bf16
  u16* waT   = (u16*)(ws + 8388608);    // 1536x1024 bf16
  u16* wpT   = (u16*)(ws + 11534336);   // 1024x1024 bf16
  u16* qkvb  = (u16*)(ws + 13631488);   // 4096x1536 bf16
  u16* Qb    = (u16*)(ws + 26214400);   // [2][16][2048][64] bf16
  u16* Kb    = (u16*)(ws + 34603008);   // [2][4][2048][64] bf16
  u16* Vtb   = (u16*)(ws + 36700160);   // [2][4][64][2048] bf16
  u16* Ob    = (u16*)(ws + 38797312);   // 4096x1024 bf16
  float2* rt = (float2*)(ws + 47185920); // 2048x32 float2 (512KB)

  k_prep<<<4864, 256, 0, stream>>>(x, wa, wp, xb, waT, wpT, rt);
  k_gemm_bt<1><<<dim3(12, 64), 256, 0, stream>>>(xb, waT, qkvb, 4096, 1536, 1024);
  k_rvt<<<3072, 320, 0, stream>>>(qkvb, rt, Qb, Kb, Vtb);
  k_attn<<<dim3(32, 16), 512, 0, stream>>>(Qb, Kb, Vtb, Ob);
  k_gemm_bt<0><<<dim3(8, 64), 256, 0, stream>>>(Ob, wpT, out, 4096, 1024, 1024);
}